// Round 8
// baseline (980.868 us; speedup 1.0000x reference)
//
#include <hip/hip_runtime.h>
#include <hip/hip_bf16.h>

// CGConv fused for MI355X (gfx950) — round 8: pipelined sorted gemm + fused aux.
//   memset(deg+hnew) -> setup(pack_w|cvt_h|hist) -> scan(1 block) ->
//   scatter(sort + permute ea->bf16 into sorted order) ->
//   gemm (2-subtile software pipeline, sequential bf16 ea, run-combined atomics) ->
//   finalize.
// R7 analysis: gemm latency-bound (Occ 2 waves/SIMD, random fp32 ea gather on
// critical path); ~150-200us fixed harness tax + ~10-15us/launch => 6 launches.

#define NODE_DIM 96
#define EDGE_DIM 64
#define NT_TILES 12       // 192 output cols = 96 gates + 96 msgs
#define KT_TILES 8        // 256 / 32
#define PACK_BLOCKS 24    // 96*64 threads / 256

typedef float  f32x4  __attribute__((ext_vector_type(4)));
typedef __bf16 bf16x8 __attribute__((ext_vector_type(8)));

__device__ __forceinline__ unsigned short bf16rne(float f) {
    unsigned int u = __float_as_uint(f);
    u += 0x7FFFu + ((u >> 16) & 1u);
    return (unsigned short)(u >> 16);
}

// ---------------------------------------------------------------------------
// Fused setup: blocks [0,24) pack W, [24,24+cvtB) convert h, rest histogram.
// ---------------------------------------------------------------------------
__global__ __launch_bounds__(256)
void setup_kernel(const float* __restrict__ We, const float* __restrict__ Wn,
                  unsigned short* __restrict__ bpack,
                  const float* __restrict__ h, unsigned short* __restrict__ hb,
                  int total8,
                  const int* __restrict__ eidx, unsigned* __restrict__ deg,
                  int E, int cvtB) {
    const int b = blockIdx.x, tid = threadIdx.x;
    if (b < PACK_BLOCKS) {
        int t = b * 256 + tid;
        if (t < KT_TILES * NT_TILES * 64) {
            int tile = t >> 6, lane = t & 63;
            int kt = tile / NT_TILES, nt = tile % NT_TILES;
            const float* W = (nt < 6) ? We : Wn;
            int n  = (nt % 6) * 16 + (lane & 15);
            int k0 = kt * 32 + (lane >> 4) * 8;
            union { unsigned short u[8]; uint4 v; } tmp;
#pragma unroll
            for (int j = 0; j < 8; ++j) tmp.u[j] = bf16rne(W[(k0 + j) * NODE_DIM + n]);
            *(uint4*)(bpack + (size_t)t * 8) = tmp.v;
        }
    } else if (b < PACK_BLOCKS + cvtB) {
        int i = (b - PACK_BLOCKS) * 256 + tid;
        if (i < total8) {
            const float4 v0 = ((const float4*)h)[i * 2];
            const float4 v1 = ((const float4*)h)[i * 2 + 1];
            union { unsigned short u[8]; uint4 v; } p;
            p.u[0] = bf16rne(v0.x); p.u[1] = bf16rne(v0.y);
            p.u[2] = bf16rne(v0.z); p.u[3] = bf16rne(v0.w);
            p.u[4] = bf16rne(v1.x); p.u[5] = bf16rne(v1.y);
            p.u[6] = bf16rne(v1.z); p.u[7] = bf16rne(v1.w);
            ((uint4*)hb)[i] = p.v;
        }
    } else {
        int e = (b - PACK_BLOCKS - cvtB) * 256 + tid;
        if (e < E) atomicAdd(deg + eidx[E + e], 1u);
    }
}

// ---------------------------------------------------------------------------
// Single-block exclusive scan over deg[0..N) -> offsets, cursor. 1024 threads.
// ---------------------------------------------------------------------------
__global__ __launch_bounds__(1024)
void scan_kernel(const unsigned* __restrict__ deg,
                 unsigned* __restrict__ offsets,
                 unsigned* __restrict__ cursor, int N) {
    __shared__ unsigned lds_w[16], lds_p[16], lds_tot;
    const int tid = threadIdx.x, lane = tid & 63, wv = tid >> 6;
    unsigned carry = 0;
    for (int base = 0; base < N; base += 1024) {
        int i = base + tid;
        unsigned v = (i < N) ? deg[i] : 0u;
        unsigned inc = v;
#pragma unroll
        for (int o = 1; o < 64; o <<= 1) {
            unsigned t = __shfl_up(inc, o, 64);
            if (lane >= o) inc += t;
        }
        if (lane == 63) lds_w[wv] = inc;
        __syncthreads();
        if (tid == 0) {
            unsigned s = 0;
#pragma unroll
            for (int k = 0; k < 16; ++k) { unsigned x = lds_w[k]; lds_p[k] = s; s += x; }
            lds_tot = s;
        }
        __syncthreads();
        unsigned excl = inc - v + lds_p[wv] + carry;
        if (i < N) { offsets[i] = excl; cursor[i] = excl; }
        carry += lds_tot;
        __syncthreads();
    }
    if (tid == 0) offsets[N] = carry;
}

// ---------------------------------------------------------------------------
// Scatter: counting-sort positions + permute ea into sorted order as bf16.
// Block = 256 = 4 waves, wave handles 64 consecutive edges.
// ---------------------------------------------------------------------------
__global__ __launch_bounds__(256)
void scatter_kernel(const int* __restrict__ eidx, const float* __restrict__ ea,
                    unsigned* __restrict__ cursor,
                    int2* __restrict__ s_sd, unsigned short* __restrict__ seab,
                    int E) {
    const int tid = threadIdx.x, wave = tid >> 6, lane = tid & 63;
    const int ebase = blockIdx.x * 256 + wave * 64;
    const int e = ebase + lane;
    unsigned pos = 0u;
    if (e < E) {
        int s = eidx[e], d = eidx[E + e];
        pos = atomicAdd(cursor + d, 1u);
        s_sd[pos] = make_int2(s, d);
    }
    // permute ea row (256B fp32 -> 128B bf16) to sorted position; 4 lanes/edge
#pragma unroll
    for (int ph = 0; ph < 4; ++ph) {
        const int el = ph * 16 + (lane >> 2);
        const int q  = lane & 3;
        const unsigned p = (unsigned)__shfl((int)pos, el, 64);
        const int eo = ebase + el;
        if (eo < E) {
            const float4* pr = (const float4*)(ea + (size_t)eo * EDGE_DIM) + q * 4;
            const float4 v0 = pr[0], v1 = pr[1], v2 = pr[2], v3 = pr[3];
            union { unsigned short u[16]; uint4 v[2]; } t;
            t.u[0]  = bf16rne(v0.x); t.u[1]  = bf16rne(v0.y);
            t.u[2]  = bf16rne(v0.z); t.u[3]  = bf16rne(v0.w);
            t.u[4]  = bf16rne(v1.x); t.u[5]  = bf16rne(v1.y);
            t.u[6]  = bf16rne(v1.z); t.u[7]  = bf16rne(v1.w);
            t.u[8]  = bf16rne(v2.x); t.u[9]  = bf16rne(v2.y);
            t.u[10] = bf16rne(v2.z); t.u[11] = bf16rne(v2.w);
            t.u[12] = bf16rne(v3.x); t.u[13] = bf16rne(v3.y);
            t.u[14] = bf16rne(v3.z); t.u[15] = bf16rne(v3.w);
            uint4* dp = (uint4*)(seab + (size_t)p * EDGE_DIM + q * 16);
            dp[0] = t.v[0]; dp[1] = t.v[1];
        }
    }
}

// ---------------------------------------------------------------------------
// GEMM over sorted rows, 2-subtile software pipeline per wave.
// Wave covers 64 rows = 2 subtiles x (mt=2 x 16 rows). Block 256 -> 256 rows.
// ---------------------------------------------------------------------------
__global__ __launch_bounds__(256, 2)
void gemm_sorted_kernel(const unsigned short* __restrict__ hb,
                        const int2* __restrict__ s_sd,
                        const unsigned short* __restrict__ seab,
                        const unsigned short* __restrict__ bpack,
                        const float* __restrict__ be,
                        const float* __restrict__ bn,
                        float* __restrict__ hnew,
                        int E) {
    const int tid  = threadIdx.x;
    const int wave = tid >> 6, lane = tid & 63;
    const int m    = lane & 15;
    const int quad = lane >> 4;
    const int wbase = (blockIdx.x * 4 + wave) * 64;

    const unsigned short* bl = bpack + lane * 8;

    float bev[6], bnv[6];
#pragma unroll
    for (int nt = 0; nt < 6; ++nt) { bev[nt] = be[nt * 16 + m]; bnv[nt] = bn[nt * 16 + m]; }

    // load sorted (src,dst) for both subtiles up front
    int2 sd[2][2];
#pragma unroll
    for (int T = 0; T < 2; ++T)
#pragma unroll
        for (int mt = 0; mt < 2; ++mt) {
            int r  = wbase + T * 32 + mt * 16 + m;
            int rg = (r < E) ? r : (E - 1);
            sd[T][mt] = s_sd[rg];
        }

    bf16x8 a[2][8];     // [mt][kt] fragments for the CURRENT subtile
    f32x4 acc[2][NT_TILES];

    auto load_a = [&](int T) {
#pragma unroll
        for (int mt = 0; mt < 2; ++mt) {
            int r  = wbase + T * 32 + mt * 16 + m;
            int rg = (r < E) ? r : (E - 1);
            const unsigned short* hs = hb + (size_t)sd[T][mt].x * NODE_DIM + quad * 8;
            const unsigned short* hd = hb + (size_t)sd[T][mt].y * NODE_DIM + quad * 8;
            const unsigned short* ep = seab + (size_t)rg * EDGE_DIM + quad * 8;
#pragma unroll
            for (int kt = 0; kt < 3; ++kt) a[mt][kt]     = *(const bf16x8*)(hs + kt * 32);
#pragma unroll
            for (int kt = 0; kt < 3; ++kt) a[mt][3 + kt] = *(const bf16x8*)(hd + kt * 32);
            a[mt][6] = *(const bf16x8*)(ep);
            a[mt][7] = *(const bf16x8*)(ep + 32);
        }
    };

    auto zero_acc = [&]() {
#pragma unroll
        for (int mt = 0; mt < 2; ++mt)
#pragma unroll
            for (int nt = 0; nt < NT_TILES; ++nt) acc[mt][nt] = (f32x4){0.f, 0.f, 0.f, 0.f};
    };

    auto mfma_all = [&]() {
#pragma unroll
        for (int kt = 0; kt < KT_TILES; ++kt) {
#pragma unroll
            for (int nt = 0; nt < NT_TILES; ++nt) {
                bf16x8 bfrag = *(const bf16x8*)(bl + (kt * NT_TILES + nt) * 512);
                acc[0][nt] = __builtin_amdgcn_mfma_f32_16x16x32_bf16(a[0][kt], bfrag, acc[0][nt], 0, 0, 0);
                acc[1][nt] = __builtin_amdgcn_mfma_f32_16x16x32_bf16(a[1][kt], bfrag, acc[1][nt], 0, 0, 0);
            }
        }
    };

    auto epilogue = [&](int T) {
#pragma unroll
        for (int mt = 0; mt < 2; ++mt) {
            int dprev = -1;
            float s[6];
#pragma unroll
            for (int r = 0; r < 4; ++r) {
                const int ee = wbase + T * 32 + mt * 16 + quad * 4 + r;
                const int d  = __shfl(sd[T][mt].y, quad * 4 + r, 64);
                if (ee >= E) continue;
                float v[6];
#pragma unroll
                for (int nt = 0; nt < 6; ++nt) {
                    float g  = acc[mt][nt][r]     + bev[nt];
                    float mm = acc[mt][nt + 6][r] + bnv[nt];
                    float gate = 1.0f / (1.0f + __expf(-g));
                    float sp   = fmaxf(mm, 0.0f) + __logf(1.0f + __expf(-fabsf(mm)));
                    v[nt] = gate * sp;
                }
                if (d != dprev) {
                    if (dprev >= 0) {
                        float* hrow = hnew + (size_t)dprev * NODE_DIM + m;
#pragma unroll
                        for (int nt = 0; nt < 6; ++nt) unsafeAtomicAdd(hrow + nt * 16, s[nt]);
                    }
#pragma unroll
                    for (int nt = 0; nt < 6; ++nt) s[nt] = v[nt];
                    dprev = d;
                } else {
#pragma unroll
                    for (int nt = 0; nt < 6; ++nt) s[nt] += v[nt];
                }
            }
            if (dprev >= 0) {
                float* hrow = hnew + (size_t)dprev * NODE_DIM + m;
#pragma unroll
                for (int nt = 0; nt < 6; ++nt) unsafeAtomicAdd(hrow + nt * 16, s[nt]);
            }
        }
    };

    // ---- software pipeline: T0 loads -> T0 mfma -> T1 loads -> T0 epilogue
    //      -> T1 mfma -> T1 epilogue. T1's load latency hides under T0 epilogue.
    load_a(0);
    zero_acc();
    mfma_all();
    load_a(1);          // issued before T0 epilogue; covered by its VALU/atomics
    epilogue(0);
    zero_acc();
    mfma_all();
    epilogue(1);
}

// ---------------------------------------------------------------------------
// finalize: out = h + hnew / max(deg,1)
// ---------------------------------------------------------------------------
__global__ void finalize_kernel(const float* __restrict__ h,
                                const float* __restrict__ hnew,
                                const unsigned* __restrict__ offsets,
                                float* __restrict__ out,
                                int total4) {
    int i = blockIdx.x * blockDim.x + threadIdx.x;
    if (i >= total4) return;
    int n = i / 24;
    unsigned deg = offsets[n + 1] - offsets[n];
    float inv = 1.0f / (float)(deg > 0u ? deg : 1u);
    float4 hv = ((const float4*)h)[i];
    float4 av = ((const float4*)hnew)[i];
    float4 o = {hv.x + av.x * inv, hv.y + av.y * inv, hv.z + av.z * inv, hv.w + av.w * inv};
    ((float4*)out)[i] = o;
}

// ---------------------------------------------------------------------------
extern "C" void kernel_launch(void* const* d_in, const int* in_sizes, int n_in,
                              void* d_out, int out_size, void* d_ws, size_t ws_size,
                              hipStream_t stream) {
    const float* h   = (const float*)d_in[0];
    const int*   ei  = (const int*)  d_in[1];
    const float* ea  = (const float*)d_in[2];
    const float* We  = (const float*)d_in[3];
    const float* be  = (const float*)d_in[4];
    const float* Wn  = (const float*)d_in[5];
    const float* bn  = (const float*)d_in[6];

    const int N = in_sizes[0] / NODE_DIM;     // 50000
    const int E = in_sizes[2] / EDGE_DIM;     // 800000
    char* ws = (char*)d_ws;

    size_t off = 0;
    auto take = [&](size_t bytes) { size_t o = off; off = (off + bytes + 511) & ~(size_t)511; return o; };
    const size_t O_BPACK = take((size_t)KT_TILES * NT_TILES * 64 * 16);   // 96 KB
    const size_t O_DEG   = take((size_t)N * 4);                           // | memset
    const size_t O_HNEW  = take((size_t)N * NODE_DIM * 4);                // | together
    const size_t O_MEMSET_END = off;
    const size_t O_OFFS  = take((size_t)(N + 1) * 4);
    const size_t O_CURS  = take((size_t)N * 4);
    const size_t O_SSD   = take((size_t)E * 8);                           // int2
    const size_t O_SEAB  = take((size_t)E * EDGE_DIM * 2);                // 102.4 MB
    const size_t O_HB    = take((size_t)N * NODE_DIM * 2);                // 9.6 MB
    (void)ws_size;

    unsigned short* bpack = (unsigned short*)(ws + O_BPACK);
    unsigned* deg   = (unsigned*)(ws + O_DEG);
    float*    hnew  = (float*)(ws + O_HNEW);
    unsigned* offs  = (unsigned*)(ws + O_OFFS);
    unsigned* curs  = (unsigned*)(ws + O_CURS);
    int2*     s_sd  = (int2*)(ws + O_SSD);
    unsigned short* seab = (unsigned short*)(ws + O_SEAB);
    unsigned short* hb   = (unsigned short*)(ws + O_HB);

    hipMemsetAsync(ws + O_DEG, 0, O_MEMSET_END - O_DEG, stream);

    const int total8 = N * NODE_DIM / 8;              // 600000
    const int cvtB   = (total8 + 255) / 256;          // 2344
    const int histB  = (E + 255) / 256;               // 3125
    setup_kernel<<<PACK_BLOCKS + cvtB + histB, 256, 0, stream>>>(
        We, Wn, bpack, h, hb, total8, ei, deg, E, cvtB);

    scan_kernel<<<1, 1024, 0, stream>>>(deg, offs, curs, N);

    scatter_kernel<<<(E + 255) / 256, 256, 0, stream>>>(ei, ea, curs, s_sd, seab, E);

    gemm_sorted_kernel<<<(E + 255) / 256, 256, 0, stream>>>(hb, s_sd, seab, bpack,
                                                            be, bn, hnew, E);

    const int total4 = N * (NODE_DIM / 4);
    finalize_kernel<<<(total4 + 255) / 256, 256, 0, stream>>>(h, hnew, offs, (float*)d_out, total4);
}